// Round 4
// baseline (122.942 us; speedup 1.0000x reference)
//
#include <hip/hip_runtime.h>
#include <math.h>

// NetVLAD: B=64, N=1024, D=512, K=64, G=16 (C=80)
#define BB 64
#define NN 1024
#define DD 512
#define KK 64
#define CC 80

typedef __attribute__((ext_vector_type(8))) short short8;  // 8 bf16 (4 VGPRs)
typedef __attribute__((ext_vector_type(4))) float f32x4;   // MFMA accumulator

union U16x8 { uint4 u; short8 s; };

// Split fp32 -> bf16 hi (truncated) + bf16 lo (truncated remainder).
// Products hi*hi + lo*hi + hi*lo give ~2^-16 relative error.
__device__ __forceinline__ void cvt_hilo8(const float* f, short8& hi, short8& lo) {
#pragma unroll
    for (int j = 0; j < 8; ++j) {
        unsigned u = __float_as_uint(f[j]);
        unsigned uh = u & 0xFFFF0000u;
        float fl = f[j] - __uint_as_float(uh);
        hi[j] = (short)(uh >> 16);
        lo[j] = (short)(__float_as_uint(fl) >> 16);
    }
}

// ---------------------------------------------------------------------------
// K0: pre-swizzle clusters (512x80 fp32) into per-lane MFMA B-frag layout,
// bf16 hi/lo. Entry (ks,q,l,dw): q = tile*2+part; c = tile*16+(l&15);
// d = ks*32+(l>>4)*8+dw*2+{0,1}. 40960 dwords = 160KB.
// ---------------------------------------------------------------------------
__global__ __launch_bounds__(256) void k_prep(
    const float* __restrict__ clusters, unsigned int* __restrict__ bfrag)
{
    int i = blockIdx.x * 256 + threadIdx.x;
    if (i >= 16 * 10 * 64 * 4) return;
    int dw = i & 3;
    int l = (i >> 2) & 63;
    int rest = i >> 8;           // 0..159
    int q = rest % 10;
    int ks = rest / 10;
    int tile = q >> 1, part = q & 1;
    int c = tile * 16 + (l & 15);
    int dbase = ks * 32 + (l >> 4) * 8 + dw * 2;
    unsigned outw = 0;
#pragma unroll
    for (int e = 0; e < 2; ++e) {
        float v = clusters[(size_t)(dbase + e) * CC + c];
        unsigned u = __float_as_uint(v);
        unsigned uh = u & 0xFFFF0000u;
        unsigned h;
        if (part == 0) h = uh >> 16;
        else {
            float fl = v - __uint_as_float(uh);
            h = __float_as_uint(fl) >> 16;
        }
        outw |= h << (16 * e);
    }
    bfrag[i] = outw;
}

// ---------------------------------------------------------------------------
// K1: scores = x @ clusters via split-bf16 MFMA (16x16x32), BN, softmax(80),
// keep first 64 -> assign + per-block column sums. Block = 64 rows, 4 waves.
// No LDS in main loop; epilogue fully in-register with direct global stores
// (4x64B segments per store instr). LDS = 1.7KB -> occupancy VGPR-bound.
// C/D layout: col = lane&15 (cluster), row = (lane>>4)*4 + reg (x-row).
// ---------------------------------------------------------------------------
__global__ __launch_bounds__(256, 4) void k_assign_mfma(
    const float* __restrict__ x,           // (B*N, D)
    const unsigned int* __restrict__ bfrag,
    const float* __restrict__ rmean,
    const float* __restrict__ rvar,
    float* __restrict__ assign,            // (B*N, K)
    float* __restrict__ asum_part)         // (1024, K)
{
    __shared__ float colp[4][64];
    __shared__ float bnm[CC], bns[CC];

    const int t = threadIdx.x;
    const int w = t >> 6;       // wave 0..3
    const int l = t & 63;       // lane
    const int row0 = blockIdx.x * 64;

    if (t < CC) {
        bnm[t] = rmean[t];
        bns[t] = rsqrtf(rvar[t] + 1e-5f);
    }

    f32x4 acc[5];
#pragma unroll
    for (int nt = 0; nt < 5; ++nt)
#pragma unroll
        for (int r = 0; r < 4; ++r) acc[nt][r] = 0.f;

    const float* xp = x + (size_t)(row0 + w * 16 + (l & 15)) * DD + (l >> 4) * 8;
    const uint4* bbase = (const uint4*)bfrag + l;

#pragma unroll 2
    for (int ks = 0; ks < 16; ++ks) {
        float4 v0 = *(const float4*)(xp + ks * 32);
        float4 v1 = *(const float4*)(xp + ks * 32 + 4);
        float f[8] = {v0.x, v0.y, v0.z, v0.w, v1.x, v1.y, v1.z, v1.w};
        short8 ah, al;
        cvt_hilo8(f, ah, al);
        const uint4* bp = bbase + (size_t)(ks * 10) * 64;
#pragma unroll
        for (int nt = 0; nt < 5; ++nt) {
            U16x8 uh, ul;
            uh.u = bp[(nt * 2 + 0) * 64];
            ul.u = bp[(nt * 2 + 1) * 64];
            acc[nt] = __builtin_amdgcn_mfma_f32_16x16x32_bf16(ah, uh.s, acc[nt], 0, 0, 0);
            acc[nt] = __builtin_amdgcn_mfma_f32_16x16x32_bf16(al, uh.s, acc[nt], 0, 0, 0);
            acc[nt] = __builtin_amdgcn_mfma_f32_16x16x32_bf16(ah, ul.s, acc[nt], 0, 0, 0);
        }
    }

    __syncthreads();   // bn tables ready

    // BN + softmax per row, fully in-register (cols of a row live in 16-lane group)
    float a[4][4];
#pragma unroll
    for (int r = 0; r < 4; ++r) {
        float sc[5];
#pragma unroll
        for (int nt = 0; nt < 5; ++nt) {
            int c = nt * 16 + (l & 15);
            sc[nt] = (acc[nt][r] - bnm[c]) * bns[c];
        }
        float m = sc[0];
#pragma unroll
        for (int nt = 1; nt < 5; ++nt) m = fmaxf(m, sc[nt]);
        m = fmaxf(m, __shfl_xor(m, 1));
        m = fmaxf(m, __shfl_xor(m, 2));
        m = fmaxf(m, __shfl_xor(m, 4));
        m = fmaxf(m, __shfl_xor(m, 8));
        float p[5], sum = 0.f;
#pragma unroll
        for (int nt = 0; nt < 5; ++nt) { p[nt] = __expf(sc[nt] - m); sum += p[nt]; }
        sum += __shfl_xor(sum, 1);
        sum += __shfl_xor(sum, 2);
        sum += __shfl_xor(sum, 4);
        sum += __shfl_xor(sum, 8);
        float rinv = 1.f / sum;
#pragma unroll
        for (int nt = 0; nt < 4; ++nt) a[nt][r] = p[nt] * rinv;
    }

    // direct global stores: per (nt,r) instr = 4 segments of 64B
    const int rbase = row0 + w * 16 + (l >> 4) * 4;
    const int cbase = l & 15;
#pragma unroll
    for (int nt = 0; nt < 4; ++nt)
#pragma unroll
        for (int r = 0; r < 4; ++r)
            assign[(size_t)(rbase + r) * KK + nt * 16 + cbase] = a[nt][r];

    // per-wave column sums -> cross-wave reduce via tiny LDS
#pragma unroll
    for (int nt = 0; nt < 4; ++nt) {
        float cs = a[nt][0] + a[nt][1] + a[nt][2] + a[nt][3];
        cs += __shfl_xor(cs, 16);
        cs += __shfl_xor(cs, 32);
        if (l < 16) colp[w][nt * 16 + l] = cs;
    }
    __syncthreads();
    if (t < 64) {
        asum_part[(size_t)blockIdx.x * KK + t] =
            colp[0][t] + colp[1][t] + colp[2][t] + colp[3][t];
    }
}

// ---------------------------------------------------------------------------
// K1b: a_sum[b,k] = sum of 16 row-tile partials
// ---------------------------------------------------------------------------
__global__ __launch_bounds__(256) void k_asum_reduce(
    const float* __restrict__ asum_part, float* __restrict__ a_sum)
{
    int i = blockIdx.x * 256 + threadIdx.x;   // 4096 = B*K
    if (i >= BB * KK) return;
    int b = i >> 6, k = i & 63;
    float s = 0.f;
#pragma unroll
    for (int tile = 0; tile < 16; ++tile)
        s += asum_part[(size_t)(b * 16 + tile) * KK + k];
    a_sum[i] = s;
}

// ---------------------------------------------------------------------------
// K2a: partial vlad GEMM over an N-chunk of 256.
// Block = (b, d-tile of 128, n-chunk of 4). 1024 blocks, 256 threads.
// ---------------------------------------------------------------------------
__global__ __launch_bounds__(256) void k_vlad_part(
    const float* __restrict__ x,       // (B*N, D)
    const float* __restrict__ assign,  // (B*N, K)
    float* __restrict__ part)          // (1024, 64*128)
{
    __shared__ float as[32][64];
    __shared__ float xs[32][128];

    const int t = threadIdx.x;
    const int b  = blockIdx.x >> 4;
    const int dt = (blockIdx.x >> 2) & 3;
    const int nc = blockIdx.x & 3;
    const int d0 = dt * 128;

    const int tx = t & 31;   // d cols tx*4..+3
    const int ty = t >> 5;   // 0..7 -> k rows ty*8..+7

    float acc[8][4];
#pragma unroll
    for (int i = 0; i < 8; ++i)
#pragma unroll
        for (int j = 0; j < 4; ++j) acc[i][j] = 0.f;

    const size_t xbase = (size_t)b * NN * DD + d0;
    const size_t abase = (size_t)b * NN * KK;
    const int nbeg = nc * 256;

    for (int n0 = nbeg; n0 < nbeg + 256; n0 += 32) {
        __syncthreads();
#pragma unroll
        for (int i = 0; i < 2; ++i) {
            int f = t + i * 256;
            int n = f >> 4, kq = f & 15;
            *(float4*)&as[n][kq * 4] =
                *(const float4*)(assign + abase + (size_t)(n0 + n) * KK + kq * 4);
        }
#pragma unroll
        for (int i = 0; i < 4; ++i) {
            int f = t + i * 256;
            int n = f >> 5, dq = f & 31;
            *(float4*)&xs[n][dq * 4] =
                *(const float4*)(x + xbase + (size_t)(n0 + n) * DD + dq * 4);
        }
        __syncthreads();
#pragma unroll 4
        for (int n = 0; n < 32; ++n) {
            float4 a0 = *(const float4*)&as[n][ty * 8];
            float4 a1 = *(const float4*)&as[n][ty * 8 + 4];
            float4 bv = *(const float4*)&xs[n][tx * 4];
            float a[8] = {a0.x, a0.y, a0.z, a0.w, a1.x, a1.y, a1.z, a1.w};
            float bb[4] = {bv.x, bv.y, bv.z, bv.w};
#pragma unroll
            for (int i = 0; i < 8; ++i)
#pragma unroll
                for (int j = 0; j < 4; ++j)
                    acc[i][j] = fmaf(a[i], bb[j], acc[i][j]);
        }
    }
    float* p = part + (size_t)blockIdx.x * (KK * 128);
#pragma unroll
    for (int i = 0; i < 8; ++i)
        *(float4*)(p + (size_t)(ty * 8 + i) * 128 + tx * 4) =
            make_float4(acc[i][0], acc[i][1], acc[i][2], acc[i][3]);
}

// ---------------------------------------------------------------------------
// K2b: reduce 4 N-chunk partials, subtract a_sum*c2, intra-norm over k,
//      staged coalesced write, global-sumsq partial. 256 blocks (b, dtile).
// ---------------------------------------------------------------------------
__global__ __launch_bounds__(256) void k_vlad_fin(
    const float* __restrict__ part,    // (1024, 64*128)
    const float* __restrict__ a_sum,   // (B, K)
    const float* __restrict__ c2,      // (K, D)
    float* __restrict__ out,           // (B, D*K)
    float* __restrict__ gsum_part)     // (B*4)
{
    __shared__ float red[8][128];
    __shared__ float sc[128];
    __shared__ float ot[128][65];

    const int t = threadIdx.x;
    const int b = blockIdx.x >> 2;
    const int dt = blockIdx.x & 3;
    const int d0 = dt * 128;

    const int tx = t & 31;
    const int ty = t >> 5;

    const float* p0 = part + (size_t)blockIdx.x * 4 * (KK * 128);

    float val[8][4];
#pragma unroll
    for (int i = 0; i < 8; ++i) {
        int k = ty * 8 + i;
        float4 s = make_float4(0.f, 0.f, 0.f, 0.f);
#pragma unroll
        for (int nc = 0; nc < 4; ++nc) {
            float4 v = *(const float4*)(p0 + (size_t)nc * (KK * 128) +
                                        (size_t)k * 128 + tx * 4);
            s.x += v.x; s.y += v.y; s.z += v.z; s.w += v.w;
        }
        float asv = a_sum[b * KK + k];
        float4 cv = *(const float4*)(c2 + (size_t)k * DD + d0 + tx * 4);
        val[i][0] = s.x - asv * cv.x;
        val[i][1] = s.y - asv * cv.y;
        val[i][2] = s.z - asv * cv.z;
        val[i][3] = s.w - asv * cv.w;
    }
    float p[4] = {0.f, 0.f, 0.f, 0.f};
#pragma unroll
    for (int i = 0; i < 8; ++i)
#pragma unroll
        for (int j = 0; j < 4; ++j) p[j] += val[i][j] * val[i][j];
    *(float4*)&red[ty][tx * 4] = make_float4(p[0], p[1], p[2], p[3]);
    __syncthreads();
    if (t < 128) {
        float s = 0.f;
#pragma unroll
        for (int g = 0; g < 8; ++g) s += red[g][t];
        float scale = 1.f / fmaxf(sqrtf(s), 1e-12f);
        sc[t] = scale;
        red[0][t] = s * scale * scale;
    }
    __syncthreads();
    if (t == 0) {
        float s = 0.f;
        for (int d = 0; d < 128; ++d) s += red[0][d];
        gsum_part[blockIdx.x] = s;
    }
#pragma unroll
    for (int i = 0; i < 8; ++i)
#pragma unroll
        for (int j = 0; j < 4; ++j)
            ot[tx * 4 + j][ty * 8 + i] = val[i][j] * sc[tx * 4 + j];
    __syncthreads();
    const size_t obase = (size_t)b * (DD * KK) + (size_t)d0 * KK;
#pragma unroll
    for (int i = 0; i < 32; ++i) {
        int f = t + i * 256;
        out[obase + f] = ot[f >> 6][f & 63];
    }
}

// ---------------------------------------------------------------------------
// K3: global L2 normalization per b
// ---------------------------------------------------------------------------
__global__ __launch_bounds__(256) void k_scale(
    float* __restrict__ out, const float* __restrict__ gsum_part)
{
    int idx = blockIdx.x * 256 + threadIdx.x;
    size_t f = (size_t)idx * 4;
    int b = (int)(f >> 15);                     // D*K = 32768 per b
    float s = gsum_part[b * 4 + 0] + gsum_part[b * 4 + 1] +
              gsum_part[b * 4 + 2] + gsum_part[b * 4 + 3];
    float scale = 1.f / fmaxf(sqrtf(s), 1e-12f);
    float4 v = *(float4*)(out + f);
    v.x *= scale; v.y *= scale; v.z *= scale; v.w *= scale;
    *(float4*)(out + f) = v;
}

extern "C" void kernel_launch(void* const* d_in, const int* in_sizes, int n_in,
                              void* d_out, int out_size, void* d_ws, size_t ws_size,
                              hipStream_t stream)
{
    const float* x        = (const float*)d_in[0];
    const float* clusters = (const float*)d_in[1];
    const float* rmean    = (const float*)d_in[2];
    const float* rvar     = (const float*)d_in[3];
    const float* c2       = (const float*)d_in[4];
    float* out = (float*)d_out;

    // workspace (floats): assign | asum_part | a_sum | gsum_part | part
    // bfrag (160KB) ALIASES part: k_prep writes it, k_assign reads it,
    // k_vlad_part overwrites it later (stream-ordered, deterministic).
    float* assign    = (float*)d_ws;                         // 4194304
    float* asum_part = assign + (size_t)BB * NN * KK;        // 1024*64
    float* a_sum     = asum_part + (size_t)1024 * KK;        // 4096
    float* gsum_part = a_sum + (size_t)BB * KK;              // 256
    float* part      = gsum_part + 256;                      // 1024*8192
    unsigned int* bfrag = (unsigned int*)part;               // 40960 dwords

    k_prep<<<160, 256, 0, stream>>>(clusters, bfrag);
    k_assign_mfma<<<1024, 256, 0, stream>>>(x, bfrag, rmean, rvar, assign, asum_part);
    k_asum_reduce<<<16, 256, 0, stream>>>(asum_part, a_sum);
    k_vlad_part<<<1024, 256, 0, stream>>>(x, assign, part);
    k_vlad_fin<<<256, 256, 0, stream>>>(part, a_sum, c2, out, gsum_part);
    k_scale<<<2048, 256, 0, stream>>>(out, gsum_part);
}

// Round 5
// 112.342 us; speedup vs baseline: 1.0944x; 1.0944x over previous
//
#include <hip/hip_runtime.h>
#include <math.h>

// NetVLAD: B=64, N=1024, D=512, K=64, G=16 (C=80)
#define BB 64
#define NN 1024
#define DD 512
#define KK 64
#define CC 80

typedef __attribute__((ext_vector_type(8))) short short8;  // 8 bf16 (4 VGPRs)
typedef __attribute__((ext_vector_type(4))) float f32x4;   // MFMA accumulator

union U16x8 { uint4 u; short8 s; };

// Split fp32 -> bf16 hi (truncated) + bf16 lo (truncated remainder).
// Products hi*hi + lo*hi + hi*lo give ~2^-16 relative error.
__device__ __forceinline__ void cvt_hilo8(const float* f, short8& hi, short8& lo) {
#pragma unroll
    for (int j = 0; j < 8; ++j) {
        unsigned u = __float_as_uint(f[j]);
        unsigned uh = u & 0xFFFF0000u;
        float fl = f[j] - __uint_as_float(uh);
        hi[j] = (short)(uh >> 16);
        lo[j] = (short)(__float_as_uint(fl) >> 16);
    }
}

// ---------------------------------------------------------------------------
// K0: pre-swizzle clusters (512x80 fp32) into per-lane MFMA B-frag layout,
// bf16 hi/lo. Entry (ks,q,l,dw): q = tile*2+part; c = tile*16+(l&15);
// d = ks*32+(l>>4)*8+dw*2+{0,1}. 40960 dwords = 160KB.
// ---------------------------------------------------------------------------
__global__ __launch_bounds__(256) void k_prep(
    const float* __restrict__ clusters, unsigned int* __restrict__ bfrag)
{
    int i = blockIdx.x * 256 + threadIdx.x;
    if (i >= 16 * 10 * 64 * 4) return;
    int dw = i & 3;
    int l = (i >> 2) & 63;
    int rest = i >> 8;           // 0..159
    int q = rest % 10;
    int ks = rest / 10;
    int tile = q >> 1, part = q & 1;
    int c = tile * 16 + (l & 15);
    int dbase = ks * 32 + (l >> 4) * 8 + dw * 2;
    unsigned outw = 0;
#pragma unroll
    for (int e = 0; e < 2; ++e) {
        float v = clusters[(size_t)(dbase + e) * CC + c];
        unsigned u = __float_as_uint(v);
        unsigned uh = u & 0xFFFF0000u;
        unsigned h;
        if (part == 0) h = uh >> 16;
        else {
            float fl = v - __uint_as_float(uh);
            h = __float_as_uint(fl) >> 16;
        }
        outw |= h << (16 * e);
    }
    bfrag[i] = outw;
}

// ---------------------------------------------------------------------------
// K1: scores = x @ clusters via split-bf16 MFMA (16x16x32), BN, softmax(80),
// keep first 64 -> assign + per-block column sums. Block = 64 rows, 4 waves.
// LDS-staged operands per K-chunk of 32:
//  - xs3[4][64][3] float4: [g][row][half(+pad)] -> staging writes and A-frag
//    reads are both ds_*_b128 with exactly 2-way bank aliasing (free).
//  - bfu[640] uint4: lane-linear B-frags shared by all 4 waves (kills the
//    4x redundant L2 re-read of the old direct-global path).
// Register prefetch of iter ks+1 globals overlaps HBM latency with MFMA.
// C/D layout: col = lane&15 (cluster), row = (lane>>4)*4 + reg (x-row).
// ---------------------------------------------------------------------------
__global__ __launch_bounds__(256) void k_assign_mfma(
    const float* __restrict__ x,           // (B*N, D)
    const unsigned int* __restrict__ bfrag,
    const float* __restrict__ rmean,
    const float* __restrict__ rvar,
    float* __restrict__ assign,            // (B*N, K)
    float* __restrict__ asum_part)         // (1024, K)
{
    __shared__ float4 xs3[4][64][3];   // 12KB (pad slot makes R/W 2-way max)
    __shared__ uint4 bfu[640];         // 10KB
    __shared__ float colp[4][64];
    __shared__ float bnm[CC], bns[CC];

    const int t = threadIdx.x;
    const int w = t >> 6;       // wave 0..3
    const int l = t & 63;       // lane
    const int row0 = blockIdx.x * 64;

    if (t < CC) {
        bnm[t] = rmean[t];
        bns[t] = rsqrtf(rvar[t] + 1e-5f);
    }

    f32x4 acc[5];
#pragma unroll
    for (int nt = 0; nt < 5; ++nt)
#pragma unroll
        for (int r = 0; r < 4; ++r) acc[nt][r] = 0.f;

    // staging roles (per thread): rows rA, rA+32 at d-quad dq
    const int rA = t >> 3;        // 0..31
    const int dq = t & 7;         // 0..7
    const int g = dq >> 1, half = dq & 1;
    const float* xg = x + (size_t)(row0 + rA) * DD + dq * 4;
    const uint4* gb0 = (const uint4*)bfrag;

    // fragment-read roles
    const int frow = w * 16 + (l & 15);
    const int fg = l >> 4;

    // prefetch ks=0
    float4 pv0 = *(const float4*)(xg);
    float4 pv1 = *(const float4*)(xg + 32 * DD);
    uint4 pb0 = gb0[t];
    uint4 pb1 = gb0[t + 256];
    uint4 pb2 = (t < 128) ? gb0[t + 512] : make_uint4(0, 0, 0, 0);

    for (int ks = 0; ks < 16; ++ks) {
        __syncthreads();   // previous compute finished reading LDS
        xs3[g][rA][half] = pv0;
        xs3[g][rA + 32][half] = pv1;
        bfu[t] = pb0;
        bfu[t + 256] = pb1;
        if (t < 128) bfu[t + 512] = pb2;
        __syncthreads();

        if (ks < 15) {     // issue next-iter globals; consumed next iter
            const float* xn = xg + (ks + 1) * 32;
            pv0 = *(const float4*)(xn);
            pv1 = *(const float4*)(xn + 32 * DD);
            const uint4* gb = gb0 + (ks + 1) * 640;
            pb0 = gb[t];
            pb1 = gb[t + 256];
            if (t < 128) pb2 = gb[t + 512];
        }

        // A-frag from LDS, convert, 15 MFMAs
        float4 a0 = xs3[fg][frow][0];
        float4 a1 = xs3[fg][frow][1];
        float f[8] = {a0.x, a0.y, a0.z, a0.w, a1.x, a1.y, a1.z, a1.w};
        short8 ah, al;
        cvt_hilo8(f, ah, al);
#pragma unroll
        for (int nt = 0; nt < 5; ++nt) {
            U16x8 uh, ul;
            uh.u = bfu[(nt * 2 + 0) * 64 + l];
            ul.u = bfu[(nt * 2 + 1) * 64 + l];
            acc[nt] = __builtin_amdgcn_mfma_f32_16x16x32_bf16(ah, uh.s, acc[nt], 0, 0, 0);
            acc[nt] = __builtin_amdgcn_mfma_f32_16x16x32_bf16(al, uh.s, acc[nt], 0, 0, 0);
            acc[nt] = __builtin_amdgcn_mfma_f32_16x16x32_bf16(ah, ul.s, acc[nt], 0, 0, 0);
        }
    }

    // BN + softmax per row, fully in-register (cols of a row live in 16-lane group)
    float a[4][4];
#pragma unroll
    for (int r = 0; r < 4; ++r) {
        float sc[5];
#pragma unroll
        for (int nt = 0; nt < 5; ++nt) {
            int c = nt * 16 + (l & 15);
            sc[nt] = (acc[nt][r] - bnm[c]) * bns[c];
        }
        float m = sc[0];
#pragma unroll
        for (int nt = 1; nt < 5; ++nt) m = fmaxf(m, sc[nt]);
        m = fmaxf(m, __shfl_xor(m, 1));
        m = fmaxf(m, __shfl_xor(m, 2));
        m = fmaxf(m, __shfl_xor(m, 4));
        m = fmaxf(m, __shfl_xor(m, 8));
        float p[5], sum = 0.f;
#pragma unroll
        for (int nt = 0; nt < 5; ++nt) { p[nt] = __expf(sc[nt] - m); sum += p[nt]; }
        sum += __shfl_xor(sum, 1);
        sum += __shfl_xor(sum, 2);
        sum += __shfl_xor(sum, 4);
        sum += __shfl_xor(sum, 8);
        float rinv = 1.f / sum;
#pragma unroll
        for (int nt = 0; nt < 4; ++nt) a[nt][r] = p[nt] * rinv;
    }

    // direct global stores: per (nt,r) instr = 4 segments of 64B
    const int rbase = row0 + w * 16 + (l >> 4) * 4;
    const int cbase = l & 15;
#pragma unroll
    for (int nt = 0; nt < 4; ++nt)
#pragma unroll
        for (int r = 0; r < 4; ++r)
            assign[(size_t)(rbase + r) * KK + nt * 16 + cbase] = a[nt][r];

    // per-wave column sums -> cross-wave reduce via tiny LDS
#pragma unroll
    for (int nt = 0; nt < 4; ++nt) {
        float cs = a[nt][0] + a[nt][1] + a[nt][2] + a[nt][3];
        cs += __shfl_xor(cs, 16);
        cs += __shfl_xor(cs, 32);
        if (l < 16) colp[w][nt * 16 + l] = cs;
    }
    __syncthreads();
    if (t < 64) {
        asum_part[(size_t)blockIdx.x * KK + t] =
            colp[0][t] + colp[1][t] + colp[2][t] + colp[3][t];
    }
}

// ---------------------------------------------------------------------------
// K1b: a_sum[b,k] = sum of 16 row-tile partials
// ---------------------------------------------------------------------------
__global__ __launch_bounds__(256) void k_asum_reduce(
    const float* __restrict__ asum_part, float* __restrict__ a_sum)
{
    int i = blockIdx.x * 256 + threadIdx.x;   // 4096 = B*K
    if (i >= BB * KK) return;
    int b = i >> 6, k = i & 63;
    float s = 0.f;
#pragma unroll
    for (int tile = 0; tile < 16; ++tile)
        s += asum_part[(size_t)(b * 16 + tile) * KK + k];
    a_sum[i] = s;
}

// ---------------------------------------------------------------------------
// K2a: partial vlad GEMM over an N-chunk of 256.
// Block = (b, d-tile of 128, n-chunk of 4). 1024 blocks, 256 threads.
// ---------------------------------------------------------------------------
__global__ __launch_bounds__(256) void k_vlad_part(
    const float* __restrict__ x,       // (B*N, D)
    const float* __restrict__ assign,  // (B*N, K)
    float* __restrict__ part)          // (1024, 64*128)
{
    __shared__ float as[32][64];
    __shared__ float xs[32][128];

    const int t = threadIdx.x;
    const int b  = blockIdx.x >> 4;
    const int dt = (blockIdx.x >> 2) & 3;
    const int nc = blockIdx.x & 3;
    const int d0 = dt * 128;

    const int tx = t & 31;   // d cols tx*4..+3
    const int ty = t >> 5;   // 0..7 -> k rows ty*8..+7

    float acc[8][4];
#pragma unroll
    for (int i = 0; i < 8; ++i)
#pragma unroll
        for (int j = 0; j < 4; ++j) acc[i][j] = 0.f;

    const size_t xbase = (size_t)b * NN * DD + d0;
    const size_t abase = (size_t)b * NN * KK;
    const int nbeg = nc * 256;

    for (int n0 = nbeg; n0 < nbeg + 256; n0 += 32) {
        __syncthreads();
#pragma unroll
        for (int i = 0; i < 2; ++i) {
            int f = t + i * 256;
            int n = f >> 4, kq = f & 15;
            *(float4*)&as[n][kq * 4] =
                *(const float4*)(assign + abase + (size_t)(n0 + n) * KK + kq * 4);
        }
#pragma unroll
        for (int i = 0; i < 4; ++i) {
            int f = t + i * 256;
            int n = f >> 5, dq = f & 31;
            *(float4*)&xs[n][dq * 4] =
                *(const float4*)(x + xbase + (size_t)(n0 + n) * DD + dq * 4);
        }
        __syncthreads();
#pragma unroll 4
        for (int n = 0; n < 32; ++n) {
            float4 a0 = *(const float4*)&as[n][ty * 8];
            float4 a1 = *(const float4*)&as[n][ty * 8 + 4];
            float4 bv = *(const float4*)&xs[n][tx * 4];
            float a[8] = {a0.x, a0.y, a0.z, a0.w, a1.x, a1.y, a1.z, a1.w};
            float bb[4] = {bv.x, bv.y, bv.z, bv.w};
#pragma unroll
            for (int i = 0; i < 8; ++i)
#pragma unroll
                for (int j = 0; j < 4; ++j)
                    acc[i][j] = fmaf(a[i], bb[j], acc[i][j]);
        }
    }
    float* p = part + (size_t)blockIdx.x * (KK * 128);
#pragma unroll
    for (int i = 0; i < 8; ++i)
        *(float4*)(p + (size_t)(ty * 8 + i) * 128 + tx * 4) =
            make_float4(acc[i][0], acc[i][1], acc[i][2], acc[i][3]);
}

// ---------------------------------------------------------------------------
// K2b: reduce 4 N-chunk partials, subtract a_sum*c2, intra-norm over k,
//      staged coalesced write, global-sumsq partial. 256 blocks (b, dtile).
// ---------------------------------------------------------------------------
__global__ __launch_bounds__(256) void k_vlad_fin(
    const float* __restrict__ part,    // (1024, 64*128)
    const float* __restrict__ a_sum,   // (B, K)
    const float* __restrict__ c2,      // (K, D)
    float* __restrict__ out,           // (B, D*K)
    float* __restrict__ gsum_part)     // (B*4)
{
    __shared__ float red[8][128];
    __shared__ float sc[128];
    __shared__ float ot[128][65];

    const int t = threadIdx.x;
    const int b = blockIdx.x >> 2;
    const int dt = blockIdx.x & 3;
    const int d0 = dt * 128;

    const int tx = t & 31;
    const int ty = t >> 5;

    const float* p0 = part + (size_t)blockIdx.x * 4 * (KK * 128);

    float val[8][4];
#pragma unroll
    for (int i = 0; i < 8; ++i) {
        int k = ty * 8 + i;
        float4 s = make_float4(0.f, 0.f, 0.f, 0.f);
#pragma unroll
        for (int nc = 0; nc < 4; ++nc) {
            float4 v = *(const float4*)(p0 + (size_t)nc * (KK * 128) +
                                        (size_t)k * 128 + tx * 4);
            s.x += v.x; s.y += v.y; s.z += v.z; s.w += v.w;
        }
        float asv = a_sum[b * KK + k];
        float4 cv = *(const float4*)(c2 + (size_t)k * DD + d0 + tx * 4);
        val[i][0] = s.x - asv * cv.x;
        val[i][1] = s.y - asv * cv.y;
        val[i][2] = s.z - asv * cv.z;
        val[i][3] = s.w - asv * cv.w;
    }
    float p[4] = {0.f, 0.f, 0.f, 0.f};
#pragma unroll
    for (int i = 0; i < 8; ++i)
#pragma unroll
        for (int j = 0; j < 4; ++j) p[j] += val[i][j] * val[i][j];
    *(float4*)&red[ty][tx * 4] = make_float4(p[0], p[1], p[2], p[3]);
    __syncthreads();
    if (t < 128) {
        float s = 0.f;
#pragma unroll
        for (int g = 0; g < 8; ++g) s += red[g][t];
        float scale = 1.f / fmaxf(sqrtf(s), 1e-12f);
        sc[t] = scale;
        red[0][t] = s * scale * scale;
    }
    __syncthreads();
    if (t == 0) {
        float s = 0.f;
        for (int d = 0; d < 128; ++d) s += red[0][d];
        gsum_part[blockIdx.x] = s;
    }
#pragma unroll
    for (int i = 0; i < 8; ++i)
#pragma unroll
        for (int j = 0; j < 4; ++j)
            ot[tx * 4 + j][ty * 8 + i] = val[i][j] * sc[tx * 4 + j];
    __syncthreads();
    const size_t obase = (size_t)b * (DD * KK) + (size_t)d0 * KK;
#pragma unroll
    for (int i = 0; i < 32; ++i) {
        int f = t + i * 256;
        out[obase + f] = ot[f >> 6][f & 63];
    }
}

// ---------------------------------------------------------------------------
// K3: global L2 normalization per b
// ---------------------------------------------------------------------------
__global__ __launch_bounds__(256) void k_scale(
    float* __restrict__ out, const float* __restrict__ gsum_part)
{
    int idx = blockIdx.x * 256 + threadIdx.x;
    size_t f = (size_t)idx * 4;
    int b = (int)(f >> 15);                     // D*K = 32768 per b
    float s = gsum_part[b * 4 + 0] + gsum_part[b * 4 + 1] +
              gsum_part[b * 4 + 2] + gsum_part[b * 4 + 3];
    float scale = 1.f / fmaxf(sqrtf(s), 1e-12f);
    float4 v = *(float4*)(out + f);
    v.x *= scale; v.y *= scale; v.z *= scale; v.w *= scale;
    *(float4*)(out + f) = v;
}

extern "C" void kernel_launch(void* const* d_in, const int* in_sizes, int n_in,
                              void* d_out, int out_size, void* d_ws, size_t ws_size,
                              hipStream_t stream)
{
    const float* x        = (const float*)d_in[0];
    const float* clusters = (const float*)d_in[1];
    const float* rmean    = (const float*)d_in[2];
    const float* rvar     = (const float*)d_in[3];
    const float* c2       = (const float*)d_in[4];
    float* out = (float*)d_out;

    // workspace (floats): assign | asum_part | a_sum | gsum_part | part
    // bfrag (160KB) ALIASES part: k_prep writes it, k_assign reads it,
    // k_vlad_part overwrites it later (stream-ordered, deterministic).
    float* assign    = (float*)d_ws;                         // 4194304
    float* asum_part = assign + (size_t)BB * NN * KK;        // 1024*64
    float* a_sum     = asum_part + (size_t)1024 * KK;        // 4096
    float* gsum_part = a_sum + (size_t)BB * KK;              // 256
    float* part      = gsum_part + 256;                      // 1024*8192
    unsigned int* bfrag = (unsigned int*)part;               // 40960 dwords

    k_prep<<<160, 256, 0, stream>>>(clusters, bfrag);
    k_assign_mfma<<<1024, 256, 0, stream>>>(x, bfrag, rmean, rvar, assign, asum_part);
    k_asum_reduce<<<16, 256, 0, stream>>>(asum_part, a_sum);
    k_vlad_part<<<1024, 256, 0, stream>>>(x, assign, part);
    k_vlad_fin<<<256, 256, 0, stream>>>(part, a_sum, c2, out, gsum_part);
    k_scale<<<2048, 256, 0, stream>>>(out, gsum_part);
}